// Round 2
// baseline (301.301 us; speedup 1.0000x reference)
//
#include <hip/hip_runtime.h>
#include <hip/hip_bf16.h>

#define B_   16
#define N_   1024
#define INF_ 256
#define NH_  4
#define DF_  64
#define HD_  256   // HEADS*OUT_F, row stride of W / h

// ---------------------------------------------------------------------------
// Kernel A: h = x @ W  (fp32), fused s_src/s_dst per-head scores.
// Block = 256 threads computes 64 rows x 64 cols (one head's D-slice).
// grid = 256 rowblocks * 4 heads = 1024
// ---------------------------------------------------------------------------
__global__ __launch_bounds__(256) void k_gemm_h(
    const float* __restrict__ x, const float* __restrict__ W,
    const float* __restrict__ a, float* __restrict__ h,
    float* __restrict__ ssrc, float* __restrict__ sdst)
{
    __shared__ float xs[64][68];   // 64 rows x 64 k (chunked), padded
    int t  = threadIdx.x;
    int bx = blockIdx.x;
    int rowblk = bx >> 2;
    int hb     = bx & 3;
    int row0   = rowblk * 64;
    int ti = t >> 4, td = t & 15;
    int r0 = ti * 4, c0 = td * 4;

    float acc[4][4];
    #pragma unroll
    for (int i = 0; i < 4; i++)
        #pragma unroll
        for (int j = 0; j < 4; j++) acc[i][j] = 0.f;

    const float* Wp = W + hb * 64 + c0;

    for (int kc = 0; kc < 4; kc++) {
        // stage x[row0..+63][kc*64..+63] -> LDS
        #pragma unroll
        for (int q = 0; q < 4; q++) {
            int r = q * 16 + ti;
            int k = td * 4;
            float4 f = *(const float4*)(x + (long)(row0 + r) * INF_ + kc * 64 + k);
            *(float4*)&xs[r][k] = f;
        }
        __syncthreads();
        for (int k = 0; k < 64; k += 4) {
            float4 xv[4];
            #pragma unroll
            for (int i = 0; i < 4; i++) xv[i] = *(const float4*)&xs[r0 + i][k];
            #pragma unroll
            for (int kk = 0; kk < 4; kk++) {
                int kg = kc * 64 + k + kk;
                float4 wv = *(const float4*)(Wp + (long)kg * HD_);
                #pragma unroll
                for (int i = 0; i < 4; i++) {
                    const float* xp = (const float*)&xv[i];
                    float xi = xp[kk];
                    acc[i][0] = fmaf(xi, wv.x, acc[i][0]);
                    acc[i][1] = fmaf(xi, wv.y, acc[i][1]);
                    acc[i][2] = fmaf(xi, wv.z, acc[i][2]);
                    acc[i][3] = fmaf(xi, wv.w, acc[i][3]);
                }
            }
        }
        __syncthreads();
    }

    // write h (fp32 scratch)
    long gbase = (long)(row0 + r0) * HD_ + hb * 64 + c0;
    #pragma unroll
    for (int i = 0; i < 4; i++) {
        float4 o; o.x = acc[i][0]; o.y = acc[i][1]; o.z = acc[i][2]; o.w = acc[i][3];
        *(float4*)&h[gbase + (long)i * HD_] = o;
    }

    // fused per-head attention scores: s = h . a_{src,dst}; a is (128, NH)
    float as[4], ad[4];
    #pragma unroll
    for (int q = 0; q < 4; q++) {
        as[q] = a[(c0 + q) * NH_ + hb];
        ad[q] = a[(64 + c0 + q) * NH_ + hb];
    }
    int b  = row0 >> 10;
    int n0 = (row0 & 1023) + r0;
    #pragma unroll
    for (int i = 0; i < 4; i++) {
        float ps = acc[i][0] * as[0] + acc[i][1] * as[1] + acc[i][2] * as[2] + acc[i][3] * as[3];
        float pd = acc[i][0] * ad[0] + acc[i][1] * ad[1] + acc[i][2] * ad[2] + acc[i][3] * ad[3];
        #pragma unroll
        for (int m = 1; m < 16; m <<= 1) {
            ps += __shfl_xor(ps, m);
            pd += __shfl_xor(pd, m);
        }
        if (td == 0) {
            ssrc[((long)b * NH_ + hb) * N_ + n0 + i] = ps;
            sdst[((long)b * NH_ + hb) * N_ + n0 + i] = pd;
        }
    }
}

// ---------------------------------------------------------------------------
// Kernel B: max_dst[b,h] = max_j s_dst[b,h,j]   (grid = 64)
// ---------------------------------------------------------------------------
__global__ __launch_bounds__(256) void k_maxdst(const float* __restrict__ sdst,
                                                float* __restrict__ mx)
{
    int bh = blockIdx.x;
    int t  = threadIdx.x;
    const float* p = sdst + (long)bh * N_;
    float m = -1e30f;
    for (int i = t; i < N_; i += 256) m = fmaxf(m, p[i]);
    #pragma unroll
    for (int s = 1; s < 64; s <<= 1) m = fmaxf(m, __shfl_xor(m, s));
    __shared__ float sm[4];
    if ((t & 63) == 0) sm[t >> 6] = m;
    __syncthreads();
    if (t == 0) mx[bh] = fmaxf(fmaxf(sm[0], sm[1]), fmaxf(sm[2], sm[3]));
}

// ---------------------------------------------------------------------------
// Kernel C: masked softmax + aggregate, fused flash-style.
// Block = 256 thr handles (b, head, 64-row i-tile); loops 16 j-chunks of 64.
// grid = 16 b * 16 itiles * 4 heads = 1024
// ---------------------------------------------------------------------------
__global__ __launch_bounds__(256) void k_attn(
    const int* __restrict__ adj, const float* __restrict__ h,
    const float* __restrict__ ssrc, const float* __restrict__ sdst,
    const float* __restrict__ mxd, float* __restrict__ out)
{
    __shared__ float sh_h[64][68];
    __shared__ float sh_w[64][68];
    __shared__ float sh_ss[64], sh_m[64], sh_den[64];

    int t  = threadIdx.x;
    int bx = blockIdx.x;
    int hh    = bx & 3;
    int itile = (bx >> 2) & 15;
    int b     = bx >> 6;
    int i0 = itile * 64;
    int bh = b * NH_ + hh;
    float mx = mxd[bh];

    if (t < 64) {
        float ss = ssrc[(long)bh * N_ + i0 + t];
        sh_ss[t] = ss;
        float e = ss + mx;               // row max = lrelu(ss_i + max_j sd_j)
        sh_m[t] = e > 0.f ? e : 0.2f * e;
    }
    __syncthreads();

    int wv = t >> 6;
    int lane = t & 63;
    int ti = t >> 4, td = t & 15;

    float pden[16];
    #pragma unroll
    for (int k = 0; k < 16; k++) pden[k] = 0.f;
    float acc[4][4];
    #pragma unroll
    for (int i = 0; i < 4; i++)
        #pragma unroll
        for (int j = 0; j < 4; j++) acc[i][j] = 0.f;

    const float* hb_ptr = h + (long)b * N_ * HD_ + hh * 64;
    const int* adj_b = adj + ((long)b * N_ + i0) * N_;
    const float* sd_ptr = sdst + (long)bh * N_;

    for (int jc = 0; jc < 16; jc++) {
        int j0 = jc * 64;
        // stage h chunk: rows j0..j0+63 of this head's 64-col slice
        #pragma unroll
        for (int q = 0; q < 4; q++) {
            int j = q * 16 + ti;
            int d = td * 4;
            float4 v = *(const float4*)&hb_ptr[(long)(j0 + j) * HD_ + d];
            *(float4*)&sh_h[j][d] = v;
        }
        // w phase: unnormalized att weights for rows i = wv + 4k, col j0+lane
        float sd = sd_ptr[j0 + lane];
        #pragma unroll
        for (int k = 0; k < 16; k++) {
            int i = wv + 4 * k;
            int av = adj_b[(long)i * N_ + j0 + lane];
            float e = sh_ss[i] + sd;
            e = e > 0.f ? e : 0.2f * e;
            float v = fmaxf(e - sh_m[i], -1e9f);
            float w = (av > 0) ? __expf(v) : 0.f;
            pden[k] += w;
            sh_w[i][lane] = w;
        }
        __syncthreads();
        // acc phase: acc[i][d] += w[i][j] * h[j][d], 4x4 register tile
        for (int jj = 0; jj < 64; jj += 4) {
            float4 hv[4];
            #pragma unroll
            for (int q = 0; q < 4; q++) hv[q] = *(const float4*)&sh_h[jj + q][td * 4];
            float4 wv4[4];
            #pragma unroll
            for (int q = 0; q < 4; q++) wv4[q] = *(const float4*)&sh_w[ti * 4 + q][jj];
            #pragma unroll
            for (int i = 0; i < 4; i++) {
                const float* wp = (const float*)&wv4[i];
                #pragma unroll
                for (int q = 0; q < 4; q++) {
                    float wj = wp[q];
                    const float* hp = (const float*)&hv[q];
                    #pragma unroll
                    for (int d = 0; d < 4; d++)
                        acc[i][d] = fmaf(wj, hp[d], acc[i][d]);
                }
            }
        }
        __syncthreads();
    }

    // denom: reduce pden across the 64 lanes of each wave
    #pragma unroll
    for (int k = 0; k < 16; k++) {
        float v = pden[k];
        #pragma unroll
        for (int s = 1; s < 64; s <<= 1) v += __shfl_xor(v, s);
        if (lane == 0) sh_den[wv + 4 * k] = v;
    }
    __syncthreads();

    // epilogue: normalize + fp32 store
    #pragma unroll
    for (int i = 0; i < 4; i++) {
        float inv = 1.0f / sh_den[ti * 4 + i];
        long base = ((long)b * N_ + i0 + ti * 4 + i) * HD_ + hh * 64 + td * 4;
        float4 o;
        o.x = acc[i][0] * inv;
        o.y = acc[i][1] * inv;
        o.z = acc[i][2] * inv;
        o.w = acc[i][3] * inv;
        *(float4*)&out[base] = o;
    }
}

extern "C" void kernel_launch(void* const* d_in, const int* in_sizes, int n_in,
                              void* d_out, int out_size, void* d_ws, size_t ws_size,
                              hipStream_t stream) {
    const float* x   = (const float*)d_in[0];
    const int*   adj = (const int*)d_in[1];
    const float* W   = (const float*)d_in[2];
    const float* a   = (const float*)d_in[3];
    float* out = (float*)d_out;

    float* h    = (float*)d_ws;                       // 16384*256 fp32 = 16 MB
    float* ssrc = h + (long)B_ * N_ * HD_;            // (B,H,N) fp32
    float* sdst = ssrc + (long)B_ * NH_ * N_;
    float* mxd  = sdst + (long)B_ * NH_ * N_;         // (B*H) fp32

    k_gemm_h<<<1024, 256, 0, stream>>>(x, W, a, h, ssrc, sdst);
    k_maxdst<<<64, 256, 0, stream>>>(sdst, mxd);
    k_attn<<<1024, 256, 0, stream>>>(adj, h, ssrc, sdst, mxd, out);
}

// Round 3
// 209.020 us; speedup vs baseline: 1.4415x; 1.4415x over previous
//
#include <hip/hip_runtime.h>
#include <hip/hip_bf16.h>

#define B_   16
#define N_   1024
#define INF_ 256
#define NH_  4
#define HD_  256
#define L2E  1.4426950408889634f

typedef __attribute__((ext_vector_type(8))) short short8;
typedef __attribute__((ext_vector_type(4))) float f32x4;

__device__ __forceinline__ float bf2f(unsigned short u) {
    union { unsigned int i; float f; } v; v.i = ((unsigned int)u) << 16; return v.f;
}
__device__ __forceinline__ unsigned short f2bf(float f) {
    union { float f; unsigned int i; } v; v.f = f;
    unsigned int x = v.i;
    return (unsigned short)((x + 0x7fffu + ((x >> 16) & 1u)) >> 16);
}

// ---------------------------------------------------------------------------
// Kernel A: h = x @ W (fp32 accum, both operands LDS-staged), writes h as
// bf16 (only consumer is the MFMA aggregate) + fused s_src/s_dst scores.
// Block = 256 thr -> 64 rows x 64 cols (one head slice). grid = 1024.
// ---------------------------------------------------------------------------
__global__ __launch_bounds__(256) void k_gemm_h(
    const float* __restrict__ x, const float* __restrict__ W,
    const float* __restrict__ a, unsigned short* __restrict__ hbf,
    float* __restrict__ ssrc, float* __restrict__ sdst)
{
    __shared__ float xs[64][68];
    __shared__ float ws[64][68];
    int t  = threadIdx.x;
    int bx = blockIdx.x;
    int rowblk = bx >> 2;
    int hb     = bx & 3;
    int row0   = rowblk * 64;
    int ti = t >> 4, td = t & 15;
    int r0 = ti * 4, c0 = td * 4;

    float acc[4][4];
    #pragma unroll
    for (int i = 0; i < 4; i++)
        #pragma unroll
        for (int j = 0; j < 4; j++) acc[i][j] = 0.f;

    for (int kc = 0; kc < 4; kc++) {
        #pragma unroll
        for (int q = 0; q < 4; q++) {
            int r = q * 16 + ti;
            *(float4*)&xs[r][td * 4] =
                *(const float4*)(x + (long)(row0 + r) * INF_ + kc * 64 + td * 4);
            *(float4*)&ws[r][td * 4] =
                *(const float4*)(W + (long)(kc * 64 + r) * HD_ + hb * 64 + td * 4);
        }
        __syncthreads();
        for (int k = 0; k < 64; k += 4) {
            float4 xv[4];
            #pragma unroll
            for (int i = 0; i < 4; i++) xv[i] = *(const float4*)&xs[r0 + i][k];
            #pragma unroll
            for (int kk = 0; kk < 4; kk++) {
                float4 wv = *(const float4*)&ws[k + kk][c0];
                #pragma unroll
                for (int i = 0; i < 4; i++) {
                    const float* xp = (const float*)&xv[i];
                    float xi = xp[kk];
                    acc[i][0] = fmaf(xi, wv.x, acc[i][0]);
                    acc[i][1] = fmaf(xi, wv.y, acc[i][1]);
                    acc[i][2] = fmaf(xi, wv.z, acc[i][2]);
                    acc[i][3] = fmaf(xi, wv.w, acc[i][3]);
                }
            }
        }
        __syncthreads();
    }

    // write h as bf16
    #pragma unroll
    for (int i = 0; i < 4; i++) {
        ushort4 o;
        o.x = f2bf(acc[i][0]); o.y = f2bf(acc[i][1]);
        o.z = f2bf(acc[i][2]); o.w = f2bf(acc[i][3]);
        *(ushort4*)&hbf[(long)(row0 + r0 + i) * HD_ + hb * 64 + c0] = o;
    }

    // fused scores: s = h . a_{src,dst}; a is (128, NH)
    float as[4], ad[4];
    #pragma unroll
    for (int q = 0; q < 4; q++) {
        as[q] = a[(c0 + q) * NH_ + hb];
        ad[q] = a[(64 + c0 + q) * NH_ + hb];
    }
    int b  = row0 >> 10;
    int n0 = (row0 & 1023) + r0;
    #pragma unroll
    for (int i = 0; i < 4; i++) {
        float ps = acc[i][0] * as[0] + acc[i][1] * as[1] + acc[i][2] * as[2] + acc[i][3] * as[3];
        float pd = acc[i][0] * ad[0] + acc[i][1] * ad[1] + acc[i][2] * ad[2] + acc[i][3] * ad[3];
        #pragma unroll
        for (int m = 1; m < 16; m <<= 1) {
            ps += __shfl_xor(ps, m);
            pd += __shfl_xor(pd, m);
        }
        if (td == 0) {
            ssrc[((long)b * NH_ + hb) * N_ + n0 + i] = ps;
            sdst[((long)b * NH_ + hb) * N_ + n0 + i] = pd;
        }
    }
}

// ---------------------------------------------------------------------------
// Kernel B: max_dst[b,h] = max_j s_dst[b,h,j]
// ---------------------------------------------------------------------------
__global__ __launch_bounds__(256) void k_maxdst(const float* __restrict__ sdst,
                                                float* __restrict__ mx)
{
    int bh = blockIdx.x;
    int t  = threadIdx.x;
    const float* p = sdst + (long)bh * N_;
    float m = -1e30f;
    for (int i = t; i < N_; i += 256) m = fmaxf(m, p[i]);
    #pragma unroll
    for (int s = 1; s < 64; s <<= 1) m = fmaxf(m, __shfl_xor(m, s));
    __shared__ float sm[4];
    if ((t & 63) == 0) sm[t >> 6] = m;
    __syncthreads();
    if (t == 0) mx[bh] = fmaxf(fmaxf(sm[0], sm[1]), fmaxf(sm[2], sm[3]));
}

// ---------------------------------------------------------------------------
// Kernel C: masked softmax + MFMA aggregate.
// grid = B * 16 itiles = 256 blocks, 1024 threads = 16 waves.
// wave -> (head hh = wave>>2, i-tile it = wave&3): one 16-row MFMA strip.
// Per 64-j chunk: stage hT bf16 in LDS; compute w directly in A-frag layout;
// 8x mfma 16x16x32_bf16; denominator from the same bf16-rounded w.
// ---------------------------------------------------------------------------
__global__ __launch_bounds__(1024) void k_attn(
    const int* __restrict__ adj, const unsigned short* __restrict__ hbf,
    const float* __restrict__ ssrc, const float* __restrict__ sdst,
    const float* __restrict__ mxd, float* __restrict__ out)
{
    __shared__ unsigned short hT[256][80];   // [d][j] bf16, stride 80 (16B-aligned rows)
    __shared__ float ss_s[4][64];            // scaled (x log2e) source scores
    __shared__ float m_s[4][64];             // scaled row max
    __shared__ float den_l[4][64];

    int t = threadIdx.x;
    int b     = blockIdx.x >> 4;
    int itile = blockIdx.x & 15;
    int i0 = itile * 64;
    int wave = t >> 6, lane = t & 63;
    int hh = wave >> 2, it = wave & 3;
    int quad = lane >> 4, l15 = lane & 15;

    if (t < 256) {
        int h = t >> 6, i = t & 63;
        int bh = b * NH_ + h;
        float ss = ssrc[(long)bh * N_ + i0 + i] * L2E;
        float mx = mxd[bh] * L2E;
        ss_s[h][i] = ss;
        float e = ss + mx;
        m_s[h][i] = fmaxf(e, 0.2f * e);
    }
    __syncthreads();

    int bh = b * NH_ + hh;
    const float* sdp = sdst + (long)bh * N_;
    const int* adjrow = adj + (long)(b * N_ + i0 + it * 16 + l15) * N_;

    float ssi = ss_s[hh][it * 16 + l15];
    float mi  = m_s[hh][it * 16 + l15];

    f32x4 accv[4];
    #pragma unroll
    for (int i = 0; i < 4; i++) accv[i] = (f32x4){0.f, 0.f, 0.f, 0.f};
    float den = 0.f;

    // staging coords: thread covers 16 d of one j column
    int jcol = t & 63;
    int dq   = (t >> 6) * 16;

    for (int jc = 0; jc < 16; jc++) {
        int j0 = jc * 64;

        // ---- stage hT[d][j] (transpose scatter, bf16) ----
        {
            const unsigned short* src = hbf + ((long)(b * N_ + j0 + jcol) << 8) + dq;
            int4 p0 = *(const int4*)src;
            int4 p1 = *(const int4*)(src + 8);
            const unsigned short* u0 = (const unsigned short*)&p0;
            const unsigned short* u1 = (const unsigned short*)&p1;
            #pragma unroll
            for (int k = 0; k < 8; k++) hT[dq + k][jcol] = u0[k];
            #pragma unroll
            for (int k = 0; k < 8; k++) hT[dq + 8 + k][jcol] = u1[k];
        }
        __syncthreads();

        // ---- w phase: A-fragments in registers ----
        short8 afrag[2];
        #pragma unroll
        for (int ks = 0; ks < 2; ks++) {
            int jb = j0 + ks * 32 + quad * 8;
            float4 s0 = *(const float4*)(sdp + jb);
            float4 s1 = *(const float4*)(sdp + jb + 4);
            int4  a0 = *(const int4*)(adjrow + jb);
            int4  a1 = *(const int4*)(adjrow + jb + 4);
            float sv[8] = {s0.x, s0.y, s0.z, s0.w, s1.x, s1.y, s1.z, s1.w};
            int   av[8] = {a0.x, a0.y, a0.z, a0.w, a1.x, a1.y, a1.z, a1.w};
            #pragma unroll
            for (int q = 0; q < 8; q++) {
                float e  = ssi + sv[q] * L2E;
                float lr = fmaxf(e, 0.2f * e);
                float v  = lr - mi;
                float w  = (av[q] > 0) ? __builtin_exp2f(v) : 0.f;
                unsigned short ub = f2bf(w);
                den += bf2f(ub);
                afrag[ks][q] = (short)ub;
            }
        }

        // ---- MFMA phase ----
        #pragma unroll
        for (int idt = 0; idt < 4; idt++) {
            const unsigned short* hrow = &hT[(hh << 6) + (idt << 4) + l15][0];
            short8 b0 = *(const short8*)(hrow + quad * 8);
            short8 b1 = *(const short8*)(hrow + 32 + quad * 8);
            accv[idt] = __builtin_amdgcn_mfma_f32_16x16x32_bf16(afrag[0], b0, accv[idt], 0, 0, 0);
            accv[idt] = __builtin_amdgcn_mfma_f32_16x16x32_bf16(afrag[1], b1, accv[idt], 0, 0, 0);
        }
        __syncthreads();
    }

    // row denominators: sum over the 4 quads
    den += __shfl_xor(den, 16);
    den += __shfl_xor(den, 32);
    if (quad == 0) den_l[hh][it * 16 + l15] = den;
    __syncthreads();

    // epilogue: C layout col=lane&15, row=quad*4+reg
    #pragma unroll
    for (int idt = 0; idt < 4; idt++) {
        #pragma unroll
        for (int r = 0; r < 4; r++) {
            int irow = it * 16 + quad * 4 + r;
            float inv = 1.0f / den_l[hh][irow];
            out[((long)(b * N_ + i0 + irow) << 8) + (hh << 6) + (idt << 4) + l15] =
                accv[idt][r] * inv;
        }
    }
}

extern "C" void kernel_launch(void* const* d_in, const int* in_sizes, int n_in,
                              void* d_out, int out_size, void* d_ws, size_t ws_size,
                              hipStream_t stream) {
    const float* x   = (const float*)d_in[0];
    const int*   adj = (const int*)d_in[1];
    const float* W   = (const float*)d_in[2];
    const float* a   = (const float*)d_in[3];
    float* out = (float*)d_out;

    unsigned short* hbf = (unsigned short*)d_ws;            // 4M bf16 = 8 MB
    float* ssrc = (float*)((char*)d_ws + (size_t)B_ * N_ * HD_ * 2);
    float* sdst = ssrc + (long)B_ * NH_ * N_;
    float* mxd  = sdst + (long)B_ * NH_ * N_;

    k_gemm_h<<<1024, 256, 0, stream>>>(x, W, a, hbf, ssrc, sdst);
    k_maxdst<<<64, 256, 0, stream>>>(sdst, mxd);
    k_attn<<<256, 1024, 0, stream>>>(adj, hbf, ssrc, sdst, mxd, out);
}

// Round 4
// 176.026 us; speedup vs baseline: 1.7117x; 1.1874x over previous
//
#include <hip/hip_runtime.h>
#include <hip/hip_bf16.h>

#define B_   16
#define N_   1024
#define INF_ 256
#define NH_  4
#define HD_  256
#define L2E  1.4426950408889634f

typedef __attribute__((ext_vector_type(8))) short short8;
typedef __attribute__((ext_vector_type(4))) float f32x4;

__device__ __forceinline__ float bf2f(unsigned short u) {
    union { unsigned int i; float f; } v; v.i = ((unsigned int)u) << 16; return v.f;
}
__device__ __forceinline__ unsigned short f2bf(float f) {
    union { float f; unsigned int i; } v; v.f = f;
    unsigned int x = v.i;
    return (unsigned short)((x + 0x7fffu + ((x >> 16) & 1u)) >> 16);
}

// ---------------------------------------------------------------------------
// Kernel P: W (256x256 fp32) -> wswz bf16 in MFMA B-frag order.
// slot = (kstep*16 + ntile)*64 + lane ; element q: k=kstep*32+(lane>>4)*8+q,
// n = ntile*16 + (lane&15). grid 32x256 (8192 slots).
// ---------------------------------------------------------------------------
__global__ __launch_bounds__(256) void k_prepw(const float* __restrict__ W,
                                               unsigned short* __restrict__ wswz)
{
    int slot = blockIdx.x * 256 + threadIdx.x;
    int kstep = slot >> 10;
    int nt    = (slot >> 6) & 15;
    int lane  = slot & 63;
    int k0 = kstep * 32 + (lane >> 4) * 8;
    int n  = nt * 16 + (lane & 15);
    ushort4 o0, o1;
    o0.x = f2bf(W[(k0 + 0) * HD_ + n]);
    o0.y = f2bf(W[(k0 + 1) * HD_ + n]);
    o0.z = f2bf(W[(k0 + 2) * HD_ + n]);
    o0.w = f2bf(W[(k0 + 3) * HD_ + n]);
    o1.x = f2bf(W[(k0 + 4) * HD_ + n]);
    o1.y = f2bf(W[(k0 + 5) * HD_ + n]);
    o1.z = f2bf(W[(k0 + 6) * HD_ + n]);
    o1.w = f2bf(W[(k0 + 7) * HD_ + n]);
    *(ushort4*)&wswz[(long)slot * 8]     = o0;
    *(ushort4*)&wswz[(long)slot * 8 + 4] = o1;
}

// ---------------------------------------------------------------------------
// Kernel A: h = x @ W via MFMA. Block = 256 thr = 4 waves (one head each),
// covers 16 rows. Writes h directly in B-frag order (hswz) + fused scores.
// grid = 1024.
// ---------------------------------------------------------------------------
__global__ __launch_bounds__(256) void k_gemm_h(
    const float* __restrict__ x, const float* __restrict__ a,
    const unsigned short* __restrict__ wswz,
    unsigned short* __restrict__ hswz,
    float* __restrict__ ssrc, float* __restrict__ sdst)
{
    __shared__ unsigned short xls[16][264];   // 16 rows x 256 k bf16, pad 8
    int t = threadIdx.x;
    int blk = blockIdx.x;
    int row0 = blk * 16;            // global row (b*1024 + n0)
    int b  = blk >> 6;
    int n0 = row0 & 1023;

    // stage x strip fp32 -> bf16 LDS (each thread: 1 row-chunk of 16)
    {
        int sr = t >> 4, sc = (t & 15) * 16;
        const float* xp = x + (long)(row0 + sr) * INF_ + sc;
        float4 v0 = ((const float4*)xp)[0];
        float4 v1 = ((const float4*)xp)[1];
        float4 v2 = ((const float4*)xp)[2];
        float4 v3 = ((const float4*)xp)[3];
        ushort4 u0 = {f2bf(v0.x), f2bf(v0.y), f2bf(v0.z), f2bf(v0.w)};
        ushort4 u1 = {f2bf(v1.x), f2bf(v1.y), f2bf(v1.z), f2bf(v1.w)};
        ushort4 u2 = {f2bf(v2.x), f2bf(v2.y), f2bf(v2.z), f2bf(v2.w)};
        ushort4 u3 = {f2bf(v3.x), f2bf(v3.y), f2bf(v3.z), f2bf(v3.w)};
        *(ushort4*)&xls[sr][sc]      = u0;
        *(ushort4*)&xls[sr][sc + 4]  = u1;
        *(ushort4*)&xls[sr][sc + 8]  = u2;
        *(ushort4*)&xls[sr][sc + 12] = u3;
    }
    __syncthreads();

    int wave = t >> 6, lane = t & 63, quad = lane >> 4, l15 = lane & 15;
    f32x4 acc[4];
    #pragma unroll
    for (int i = 0; i < 4; i++) acc[i] = (f32x4){0.f, 0.f, 0.f, 0.f};

    #pragma unroll
    for (int ks = 0; ks < 8; ks++) {
        short8 af = *(const short8*)&xls[l15][ks * 32 + quad * 8];
        #pragma unroll
        for (int nt = 0; nt < 4; nt++) {
            short8 bf = *(const short8*)(wswz +
                ((long)((ks * 16 + wave * 4 + nt) * 64 + lane)) * 8);
            acc[nt] = __builtin_amdgcn_mfma_f32_16x16x32_bf16(af, bf, acc[nt], 0, 0, 0);
        }
    }

    // store h in B-frag order: value (nt,r) is h[row0+quad*4+r][wave*64+nt*16+l15]
    int q0 = (quad & 1) * 4;
    int qd = ((row0 & 31) + quad * 4) >> 3;
    long bj32 = row0 >> 5;
    #pragma unroll
    for (int nt = 0; nt < 4; nt++) {
        int dg = wave * 4 + nt;
        long idx8 = (bj32 * 16 + dg) * 64 + qd * 16 + l15;
        ushort4 o = {f2bf(acc[nt][0]), f2bf(acc[nt][1]),
                     f2bf(acc[nt][2]), f2bf(acc[nt][3])};
        *(ushort4*)&hswz[idx8 * 8 + q0] = o;
    }

    // fused scores (fp32 acc): s = h . a_{src,dst}; a is (128, NH)
    float as_[4], ad_[4];
    #pragma unroll
    for (int nt = 0; nt < 4; nt++) {
        int d = nt * 16 + l15;
        as_[nt] = a[d * NH_ + wave];
        ad_[nt] = a[(64 + d) * NH_ + wave];
    }
    #pragma unroll
    for (int r = 0; r < 4; r++) {
        float ps = acc[0][r] * as_[0] + acc[1][r] * as_[1]
                 + acc[2][r] * as_[2] + acc[3][r] * as_[3];
        float pd = acc[0][r] * ad_[0] + acc[1][r] * ad_[1]
                 + acc[2][r] * ad_[2] + acc[3][r] * ad_[3];
        #pragma unroll
        for (int m = 1; m < 16; m <<= 1) {
            ps += __shfl_xor(ps, m);
            pd += __shfl_xor(pd, m);
        }
        if (l15 == 0) {
            int row = n0 + quad * 4 + r;
            ssrc[((long)b * NH_ + wave) * N_ + row] = ps;
            sdst[((long)b * NH_ + wave) * N_ + row] = pd;
        }
    }
}

// ---------------------------------------------------------------------------
// Kernel B: max_dst[b,h] = max_j s_dst[b,h,j]
// ---------------------------------------------------------------------------
__global__ __launch_bounds__(256) void k_maxdst(const float* __restrict__ sdst,
                                                float* __restrict__ mx)
{
    int bh = blockIdx.x;
    int t  = threadIdx.x;
    const float* p = sdst + (long)bh * N_;
    float m = -1e30f;
    for (int i = t; i < N_; i += 256) m = fmaxf(m, p[i]);
    #pragma unroll
    for (int s = 1; s < 64; s <<= 1) m = fmaxf(m, __shfl_xor(m, s));
    __shared__ float sm[4];
    if ((t & 63) == 0) sm[t >> 6] = m;
    __syncthreads();
    if (t == 0) mx[bh] = fmaxf(fmaxf(sm[0], sm[1]), fmaxf(sm[2], sm[3]));
}

// ---------------------------------------------------------------------------
// Kernel C: masked softmax + MFMA aggregate, barrier-free j-loop.
// grid = 16 b * 32 itiles = 512 blocks, 512 thr = 8 waves (4 hh x 2 it).
// Per 32-j chunk: B-frags direct from hswz (coalesced global, L2-hot),
// w A-frag from adj+scores in registers, 4 MFMAs, den from bf16 w.
// ---------------------------------------------------------------------------
__global__ __launch_bounds__(512) void k_attn(
    const int* __restrict__ adj, const unsigned short* __restrict__ hswz,
    const float* __restrict__ ssrc, const float* __restrict__ sdst,
    const float* __restrict__ mxd, float* __restrict__ out)
{
    __shared__ float ss_s[4][32], m_s[4][32], den_l[4][32];

    int t = threadIdx.x;
    int b     = blockIdx.x >> 5;
    int itile = blockIdx.x & 31;
    int i0 = itile * 32;
    int wave = t >> 6, lane = t & 63, quad = lane >> 4, l15 = lane & 15;
    int hh = wave & 3, it = wave >> 2;

    if (t < 128) {
        int h = t >> 5, i = t & 31;
        float ss = ssrc[((long)b * NH_ + h) * N_ + i0 + i] * L2E;
        float mxv = mxd[b * NH_ + h] * L2E;
        ss_s[h][i] = ss;
        float e = ss + mxv;
        m_s[h][i] = fmaxf(e, 0.2f * e);
    }
    __syncthreads();

    int irow = it * 16 + l15;
    float ssi = ss_s[hh][irow];
    float mi  = m_s[hh][irow];
    const float* sdp = sdst + ((long)b * NH_ + hh) * N_;
    const int* adjrow = adj + ((long)b * N_ + i0 + irow) * N_;

    f32x4 acc[4];
    #pragma unroll
    for (int i = 0; i < 4; i++) acc[i] = (f32x4){0.f, 0.f, 0.f, 0.f};
    float den = 0.f;

    #pragma unroll 2
    for (int jc = 0; jc < 32; jc++) {
        int j0 = jc * 32;
        // ---- A-frag: w for (row=irow, j = j0 + quad*8 + q) ----
        float4 s0 = *(const float4*)(sdp + j0 + quad * 8);
        float4 s1 = *(const float4*)(sdp + j0 + quad * 8 + 4);
        int4  a0 = *(const int4*)(adjrow + j0 + quad * 8);
        int4  a1 = *(const int4*)(adjrow + j0 + quad * 8 + 4);
        float sv[8] = {s0.x, s0.y, s0.z, s0.w, s1.x, s1.y, s1.z, s1.w};
        int   av[8] = {a0.x, a0.y, a0.z, a0.w, a1.x, a1.y, a1.z, a1.w};
        short8 af;
        #pragma unroll
        for (int q = 0; q < 8; q++) {
            float e  = ssi + sv[q] * L2E;
            float lr = fmaxf(e, 0.2f * e);
            float w  = (av[q] > 0) ? __builtin_exp2f(lr - mi) : 0.f;
            unsigned short ub = f2bf(w);
            den += bf2f(ub);
            af[q] = (short)ub;
        }
        // ---- B-frags from hswz + MFMA ----
        long base8 = ((long)(b * 32) + jc) * 1024;
        #pragma unroll
        for (int idt = 0; idt < 4; idt++) {
            int dg = hh * 4 + idt;
            short8 bf = *(const short8*)(hswz + (base8 + dg * 64 + lane) * 8);
            acc[idt] = __builtin_amdgcn_mfma_f32_16x16x32_bf16(af, bf, acc[idt], 0, 0, 0);
        }
    }

    den += __shfl_xor(den, 16);
    den += __shfl_xor(den, 32);
    if (quad == 0) den_l[hh][irow] = den;
    __syncthreads();

    // epilogue: C layout col=l15, row=quad*4+r
    #pragma unroll
    for (int idt = 0; idt < 4; idt++) {
        #pragma unroll
        for (int r = 0; r < 4; r++) {
            int ir = it * 16 + quad * 4 + r;
            float inv = 1.0f / den_l[hh][ir];
            out[((long)b * N_ + i0 + ir) * HD_ + hh * 64 + idt * 16 + l15] =
                acc[idt][r] * inv;
        }
    }
}

extern "C" void kernel_launch(void* const* d_in, const int* in_sizes, int n_in,
                              void* d_out, int out_size, void* d_ws, size_t ws_size,
                              hipStream_t stream) {
    const float* x   = (const float*)d_in[0];
    const int*   adj = (const int*)d_in[1];
    const float* W   = (const float*)d_in[2];
    const float* a   = (const float*)d_in[3];
    float* out = (float*)d_out;

    unsigned short* hswz = (unsigned short*)d_ws;                 // 4.19M sh = 8 MB
    unsigned short* wswz = hswz + (long)B_ * N_ * HD_;            // 64K sh
    float* ssrc = (float*)(wswz + INF_ * HD_);
    float* sdst = ssrc + (long)B_ * NH_ * N_;
    float* mxd  = sdst + (long)B_ * NH_ * N_;

    k_prepw<<<32, 256, 0, stream>>>(W, wswz);
    k_gemm_h<<<1024, 256, 0, stream>>>(x, a, wswz, hswz, ssrc, sdst);
    k_maxdst<<<64, 256, 0, stream>>>(sdst, mxd);
    k_attn<<<512, 512, 0, stream>>>(adj, hswz, ssrc, sdst, mxd, out);
}

// Round 5
// 175.507 us; speedup vs baseline: 1.7167x; 1.0030x over previous
//
#include <hip/hip_runtime.h>
#include <hip/hip_bf16.h>

#define B_   16
#define N_   1024
#define INF_ 256
#define NH_  4
#define HD_  256
#define L2E  1.4426950408889634f

typedef __attribute__((ext_vector_type(8))) short short8;
typedef __attribute__((ext_vector_type(4))) float f32x4;

__device__ __forceinline__ float bf2f(unsigned short u) {
    union { unsigned int i; float f; } v; v.i = ((unsigned int)u) << 16; return v.f;
}
__device__ __forceinline__ unsigned short f2bf(float f) {
    union { float f; unsigned int i; } v; v.f = f;
    unsigned int x = v.i;
    return (unsigned short)((x + 0x7fffu + ((x >> 16) & 1u)) >> 16);
}

// ---------------------------------------------------------------------------
// Kernel P: W (256x256 fp32) -> wswz bf16 in MFMA B-frag order.
// slot = (kstep*16 + ntile)*64 + lane; elem q: k=kstep*32+(lane>>4)*8+q,
// n = ntile*16 + (lane&15).
// ---------------------------------------------------------------------------
__global__ __launch_bounds__(256) void k_prepw(const float* __restrict__ W,
                                               unsigned short* __restrict__ wswz)
{
    int slot = blockIdx.x * 256 + threadIdx.x;
    int kstep = slot >> 10;
    int nt    = (slot >> 6) & 15;
    int lane  = slot & 63;
    int k0 = kstep * 32 + (lane >> 4) * 8;
    int n  = nt * 16 + (lane & 15);
    ushort4 o0, o1;
    o0.x = f2bf(W[(k0 + 0) * HD_ + n]);
    o0.y = f2bf(W[(k0 + 1) * HD_ + n]);
    o0.z = f2bf(W[(k0 + 2) * HD_ + n]);
    o0.w = f2bf(W[(k0 + 3) * HD_ + n]);
    o1.x = f2bf(W[(k0 + 4) * HD_ + n]);
    o1.y = f2bf(W[(k0 + 5) * HD_ + n]);
    o1.z = f2bf(W[(k0 + 6) * HD_ + n]);
    o1.w = f2bf(W[(k0 + 7) * HD_ + n]);
    *(ushort4*)&wswz[(long)slot * 8]     = o0;
    *(ushort4*)&wswz[(long)slot * 8 + 4] = o1;
}

// ---------------------------------------------------------------------------
// Kernel M: pack adj into A-frag-ordered bitmask.
// pb uint index = ((b*64+it)*64+lane)*8 + gw ; byte jl of that uint holds
// bits q for (row = it*16+(lane&15), j = (gw*4+jl)*32 + (lane>>4)*8 + q).
// ---------------------------------------------------------------------------
__global__ __launch_bounds__(256) void k_pack(const int* __restrict__ adj,
                                              unsigned int* __restrict__ pb)
{
    int g = blockIdx.x * 256 + threadIdx.x;      // [0, 524288)
    int gw   = g & 7;
    int lane = (g >> 3) & 63;
    int it   = (g >> 9) & 63;
    int b    = g >> 15;
    int row  = it * 16 + (lane & 15);
    int quad = lane >> 4;
    const int* ar = adj + ((long)(b * N_ + row) << 10);
    unsigned int u = 0;
    #pragma unroll
    for (int jl = 0; jl < 4; jl++) {
        int j0 = (gw * 4 + jl) * 32 + quad * 8;
        int4 a0 = *(const int4*)(ar + j0);
        int4 a1 = *(const int4*)(ar + j0 + 4);
        u |= ((unsigned)a0.x) << (jl * 8 + 0);
        u |= ((unsigned)a0.y) << (jl * 8 + 1);
        u |= ((unsigned)a0.z) << (jl * 8 + 2);
        u |= ((unsigned)a0.w) << (jl * 8 + 3);
        u |= ((unsigned)a1.x) << (jl * 8 + 4);
        u |= ((unsigned)a1.y) << (jl * 8 + 5);
        u |= ((unsigned)a1.z) << (jl * 8 + 6);
        u |= ((unsigned)a1.w) << (jl * 8 + 7);
    }
    pb[g] = u;
}

// ---------------------------------------------------------------------------
// Kernel A: h = x @ W via MFMA, W-frags resident in registers.
// Block 256 thr = 4 waves (one head each); 2 strips of 16 rows per block.
// grid = 512. Emits hswz (B-frag order bf16) + scores pre-scaled by log2e.
// ---------------------------------------------------------------------------
__global__ __launch_bounds__(256, 2) void k_gemm_h(
    const float* __restrict__ x, const float* __restrict__ a,
    const unsigned short* __restrict__ wswz,
    unsigned short* __restrict__ hswz,
    float* __restrict__ ssrc, float* __restrict__ sdst)
{
    __shared__ unsigned short xf[2][4096];   // frag-linear x, double-buffered
    int t = threadIdx.x;
    int wave = t >> 6, lane = t & 63, quad = lane >> 4, l15 = lane & 15;

    // resident W fragments for this wave's head: 32 x short8 = 128 VGPR
    short8 bw[8][4];
    #pragma unroll
    for (int ks = 0; ks < 8; ks++)
        #pragma unroll
        for (int nt = 0; nt < 4; nt++)
            bw[ks][nt] = *(const short8*)(wswz +
                ((long)((ks * 16 + wave * 4 + nt) * 64 + lane)) * 8);

    // staging coords
    int sr = t >> 4, c = t & 15;
    int ks0 = c >> 1, qA = (c & 1) * 2;

    float as_[4], ad_[4];
    #pragma unroll
    for (int nt = 0; nt < 4; nt++) {
        int d = nt * 16 + l15;
        as_[nt] = a[d * NH_ + wave];
        ad_[nt] = a[(64 + d) * NH_ + wave];
    }

    for (int s = 0; s < 2; s++) {
        int row0 = (blockIdx.x * 2 + s) * 16;
        int b  = row0 >> 10;
        int n0 = row0 & 1023;
        unsigned short* xb = &xf[s][0];

        // stage x strip -> bf16 frag-linear LDS (swizzled on ks parity)
        {
            const float* xp = x + (long)(row0 + sr) * INF_ + c * 16;
            float4 v0 = ((const float4*)xp)[0];
            float4 v1 = ((const float4*)xp)[1];
            float4 v2 = ((const float4*)xp)[2];
            float4 v3 = ((const float4*)xp)[3];
            short8 u0, u1;
            u0[0] = (short)f2bf(v0.x); u0[1] = (short)f2bf(v0.y);
            u0[2] = (short)f2bf(v0.z); u0[3] = (short)f2bf(v0.w);
            u0[4] = (short)f2bf(v1.x); u0[5] = (short)f2bf(v1.y);
            u0[6] = (short)f2bf(v1.z); u0[7] = (short)f2bf(v1.w);
            u1[0] = (short)f2bf(v2.x); u1[1] = (short)f2bf(v2.y);
            u1[2] = (short)f2bf(v2.z); u1[3] = (short)f2bf(v2.w);
            u1[4] = (short)f2bf(v3.x); u1[5] = (short)f2bf(v3.y);
            u1[6] = (short)f2bf(v3.z); u1[7] = (short)f2bf(v3.w);
            int sw = (ks0 & 1) << 2;
            int i1 = ks0 * 64 + (((qA    ) * 16 + sr) ^ sw);
            int i2 = ks0 * 64 + (((qA + 1) * 16 + sr) ^ sw);
            *(short8*)(xb + i1 * 8) = u0;
            *(short8*)(xb + i2 * 8) = u1;
        }
        __syncthreads();

        f32x4 acc[4];
        #pragma unroll
        for (int i = 0; i < 4; i++) acc[i] = (f32x4){0.f, 0.f, 0.f, 0.f};

        #pragma unroll
        for (int ks = 0; ks < 8; ks++) {
            short8 af = *(const short8*)(xb +
                (ks * 64 + (lane ^ ((ks & 1) << 2))) * 8);
            #pragma unroll
            for (int nt = 0; nt < 4; nt++)
                acc[nt] = __builtin_amdgcn_mfma_f32_16x16x32_bf16(af, bw[ks][nt], acc[nt], 0, 0, 0);
        }

        // hswz store (B-frag order for k_attn)
        int q0 = (quad & 1) * 4;
        int qd = ((row0 & 31) >> 3) + (quad >> 1);
        long bj32 = row0 >> 5;
        #pragma unroll
        for (int nt = 0; nt < 4; nt++) {
            int dg = wave * 4 + nt;
            long idx8 = (bj32 * 16 + dg) * 64 + qd * 16 + l15;
            ushort4 o = {f2bf(acc[nt][0]), f2bf(acc[nt][1]),
                         f2bf(acc[nt][2]), f2bf(acc[nt][3])};
            *(ushort4*)&hswz[idx8 * 8 + q0] = o;
        }

        // fused scores, pre-scaled by log2(e)
        #pragma unroll
        for (int r = 0; r < 4; r++) {
            float ps = acc[0][r] * as_[0] + acc[1][r] * as_[1]
                     + acc[2][r] * as_[2] + acc[3][r] * as_[3];
            float pd = acc[0][r] * ad_[0] + acc[1][r] * ad_[1]
                     + acc[2][r] * ad_[2] + acc[3][r] * ad_[3];
            #pragma unroll
            for (int m = 1; m < 16; m <<= 1) {
                ps += __shfl_xor(ps, m);
                pd += __shfl_xor(pd, m);
            }
            if (l15 == 0) {
                int row = n0 + quad * 4 + r;
                ssrc[((long)b * NH_ + wave) * N_ + row] = ps * L2E;
                sdst[((long)b * NH_ + wave) * N_ + row] = pd * L2E;
            }
        }
    }
}

// ---------------------------------------------------------------------------
// Kernel C: masked softmax + MFMA aggregate, j-split waves, barrier-free loop.
// grid = 16 b * 64 itiles(16 rows) = 1024 blocks x 512 thr = 8 waves
// (hh = wave&3, jhalf = wave>>2). Mask preloaded as one uint4/thread.
// ---------------------------------------------------------------------------
__global__ __launch_bounds__(512, 6) void k_attn(
    const unsigned int* __restrict__ pb, const unsigned short* __restrict__ hswz,
    const float* __restrict__ ssrc, const float* __restrict__ sdst,
    float* __restrict__ out)
{
    __shared__ float ss_s[4][16];
    __shared__ float accb[4][64][20];   // padded: 16B-aligned, conflict-lean
    __shared__ float denb[4][64];

    int t  = threadIdx.x;
    int bx = blockIdx.x;
    int b  = bx >> 6, it = bx & 63;
    int i0 = it * 16;
    int wave = t >> 6, lane = t & 63, quad = lane >> 4, l15 = lane & 15;
    int hh = wave & 3, jh = wave >> 2;

    if (t < 64) {
        int h = t >> 4, i = t & 15;
        ss_s[h][i] = ssrc[((long)(b * NH_ + h)) * N_ + i0 + i];
    }
    __syncthreads();

    float ssi = ss_s[hh][l15];
    const float* sdp = sdst + ((long)(b * NH_ + hh)) * N_ + jh * 512;
    uint4 mr = *(const uint4*)(pb + ((long)((b * 64 + it) * 64 + lane)) * 8 + jh * 4);

    f32x4 acc[4];
    #pragma unroll
    for (int i = 0; i < 4; i++) acc[i] = (f32x4){0.f, 0.f, 0.f, 0.f};
    float den = 0.f;

    #pragma unroll 4
    for (int jc = 0; jc < 16; jc++) {
        unsigned int mwd = (jc & 8) ? ((jc & 4) ? mr.w : mr.z)
                                    : ((jc & 4) ? mr.y : mr.x);
        unsigned int byv = (mwd >> ((jc & 3) * 8)) & 0xffu;

        const float* sj = sdp + jc * 32 + quad * 8;
        float4 s0 = *(const float4*)sj;
        float4 s1 = *(const float4*)(sj + 4);
        float sv[8] = {s0.x, s0.y, s0.z, s0.w, s1.x, s1.y, s1.z, s1.w};

        short8 af;
        #pragma unroll
        for (int q = 0; q < 8; q++) {
            float e  = ssi + sv[q];
            float lr = fmaxf(e, 0.2f * e);
            float w  = __builtin_exp2f(lr);
            w = ((byv >> q) & 1u) ? w : 0.0f;
            unsigned short ub = f2bf(w);
            den += bf2f(ub);
            af[q] = (short)ub;
        }

        long s8 = ((long)(b * 32 + jh * 16 + jc)) * 16 * 64;
        #pragma unroll
        for (int idt = 0; idt < 4; idt++) {
            int dg = hh * 4 + idt;
            short8 bf = *(const short8*)(hswz + (s8 + dg * 64 + lane) * 8);
            acc[idt] = __builtin_amdgcn_mfma_f32_16x16x32_bf16(af, bf, acc[idt], 0, 0, 0);
        }
    }

    if (jh == 1) {
        #pragma unroll
        for (int idt = 0; idt < 4; idt++)
            *(f32x4*)&accb[hh][lane][idt * 4] = acc[idt];
        denb[hh][lane] = den;
    }
    __syncthreads();

    if (jh == 0) {
        den += denb[hh][lane];
        den += __shfl_xor(den, 16);
        den += __shfl_xor(den, 32);
        float dv[4];
        #pragma unroll
        for (int r = 0; r < 4; r++)
            dv[r] = 1.0f / __shfl(den, quad * 4 + r);
        #pragma unroll
        for (int idt = 0; idt < 4; idt++) {
            f32x4 other = *(const f32x4*)&accb[hh][lane][idt * 4];
            #pragma unroll
            for (int r = 0; r < 4; r++) {
                int irow = i0 + quad * 4 + r;
                out[((long)(b * N_ + irow)) * HD_ + hh * 64 + idt * 16 + l15] =
                    (acc[idt][r] + other[r]) * dv[r];
            }
        }
    }
}

extern "C" void kernel_launch(void* const* d_in, const int* in_sizes, int n_in,
                              void* d_out, int out_size, void* d_ws, size_t ws_size,
                              hipStream_t stream) {
    const float* x   = (const float*)d_in[0];
    const int*   adj = (const int*)d_in[1];
    const float* W   = (const float*)d_in[2];
    const float* a   = (const float*)d_in[3];
    float* out = (float*)d_out;

    unsigned int* pb      = (unsigned int*)d_ws;                       // 2 MB
    unsigned short* hswz  = (unsigned short*)(pb + 524288);            // 8 MB
    unsigned short* wswz  = hswz + (long)B_ * N_ * HD_;                // 128 KB
    float* ssrc = (float*)(wswz + INF_ * HD_);
    float* sdst = ssrc + (long)B_ * NH_ * N_;

    k_prepw<<<32, 256, 0, stream>>>(W, wswz);
    k_pack<<<2048, 256, 0, stream>>>(adj, pb);
    k_gemm_h<<<512, 256, 0, stream>>>(x, a, wswz, hswz, ssrc, sdst);
    k_attn<<<1024, 512, 0, stream>>>(pb, hswz, ssrc, sdst, out);
}

// Round 6
// 156.039 us; speedup vs baseline: 1.9309x; 1.1248x over previous
//
#include <hip/hip_runtime.h>
#include <hip/hip_bf16.h>

#define B_   16
#define N_   1024
#define INF_ 256
#define NH_  4
#define HD_  256
#define L2E  1.4426950408889634f

typedef __attribute__((ext_vector_type(8))) short short8;
typedef __attribute__((ext_vector_type(4))) float f32x4;

__device__ __forceinline__ float bf2f(unsigned short u) {
    union { unsigned int i; float f; } v; v.i = ((unsigned int)u) << 16; return v.f;
}
__device__ __forceinline__ unsigned short f2bf(float f) {
    union { float f; unsigned int i; } v; v.f = f;
    unsigned int x = v.i;
    return (unsigned short)((x + 0x7fffu + ((x >> 16) & 1u)) >> 16);
}

// ---------------------------------------------------------------------------
// Kernel PREP (fused):
//  blocks [0,2048): pack adj -> row-major bitmask pb[row][word] (uint32,
//    bit p of word w = adj[row][w*32+p]; adj values are exactly 0/1).
//    Each lane builds one word from 8 int4 loads (L1 absorbs the stride).
//  blocks [2048,2080): W fp32 -> wswz bf16 in MFMA B-frag order.
// ---------------------------------------------------------------------------
__global__ __launch_bounds__(256) void k_prep(const int* __restrict__ adj,
                                              const float* __restrict__ W,
                                              unsigned int* __restrict__ pb,
                                              unsigned short* __restrict__ wswz)
{
    int bx = blockIdx.x, t = threadIdx.x;
    if (bx < 2048) {
        int wave = t >> 6, lane = t & 63;
        int row = bx * 8 + wave * 2 + (lane >> 5);   // [0, 16384)
        int w   = lane & 31;
        const int4* ar = (const int4*)(adj + ((long)row << 10) + w * 32);
        unsigned int u = 0;
        #pragma unroll
        for (int k = 0; k < 8; k++) {
            int4 a = ar[k];
            u |= ((unsigned)a.x) << (4 * k);
            u |= ((unsigned)a.y) << (4 * k + 1);
            u |= ((unsigned)a.z) << (4 * k + 2);
            u |= ((unsigned)a.w) << (4 * k + 3);
        }
        pb[((long)row << 5) + w] = u;
    } else {
        int slot = (bx - 2048) * 256 + t;
        int kstep = slot >> 10;
        int nt    = (slot >> 6) & 15;
        int lane  = slot & 63;
        int k0 = kstep * 32 + (lane >> 4) * 8;
        int n  = nt * 16 + (lane & 15);
        ushort4 o0, o1;
        o0.x = f2bf(W[(k0 + 0) * HD_ + n]);
        o0.y = f2bf(W[(k0 + 1) * HD_ + n]);
        o0.z = f2bf(W[(k0 + 2) * HD_ + n]);
        o0.w = f2bf(W[(k0 + 3) * HD_ + n]);
        o1.x = f2bf(W[(k0 + 4) * HD_ + n]);
        o1.y = f2bf(W[(k0 + 5) * HD_ + n]);
        o1.z = f2bf(W[(k0 + 6) * HD_ + n]);
        o1.w = f2bf(W[(k0 + 7) * HD_ + n]);
        *(ushort4*)&wswz[(long)slot * 8]     = o0;
        *(ushort4*)&wswz[(long)slot * 8 + 4] = o1;
    }
}

// ---------------------------------------------------------------------------
// Kernel A (round-4 form): h = x @ W via MFMA, W-frags from L2 in-loop.
// Block = 256 thr = 4 waves (one head each), 16 rows. grid = 1024.
// Emits hswz (B-frag order bf16) + scores pre-scaled by log2(e).
// ---------------------------------------------------------------------------
__global__ __launch_bounds__(256) void k_gemm_h(
    const float* __restrict__ x, const float* __restrict__ a,
    const unsigned short* __restrict__ wswz,
    unsigned short* __restrict__ hswz,
    float* __restrict__ ssrc, float* __restrict__ sdst)
{
    __shared__ unsigned short xls[16][264];
    int t = threadIdx.x;
    int blk = blockIdx.x;
    int row0 = blk * 16;
    int b  = blk >> 6;
    int n0 = row0 & 1023;

    {
        int sr = t >> 4, sc = (t & 15) * 16;
        const float* xp = x + (long)(row0 + sr) * INF_ + sc;
        float4 v0 = ((const float4*)xp)[0];
        float4 v1 = ((const float4*)xp)[1];
        float4 v2 = ((const float4*)xp)[2];
        float4 v3 = ((const float4*)xp)[3];
        ushort4 u0 = {f2bf(v0.x), f2bf(v0.y), f2bf(v0.z), f2bf(v0.w)};
        ushort4 u1 = {f2bf(v1.x), f2bf(v1.y), f2bf(v1.z), f2bf(v1.w)};
        ushort4 u2 = {f2bf(v2.x), f2bf(v2.y), f2bf(v2.z), f2bf(v2.w)};
        ushort4 u3 = {f2bf(v3.x), f2bf(v3.y), f2bf(v3.z), f2bf(v3.w)};
        *(ushort4*)&xls[sr][sc]      = u0;
        *(ushort4*)&xls[sr][sc + 4]  = u1;
        *(ushort4*)&xls[sr][sc + 8]  = u2;
        *(ushort4*)&xls[sr][sc + 12] = u3;
    }
    __syncthreads();

    int wave = t >> 6, lane = t & 63, quad = lane >> 4, l15 = lane & 15;
    f32x4 acc[4];
    #pragma unroll
    for (int i = 0; i < 4; i++) acc[i] = (f32x4){0.f, 0.f, 0.f, 0.f};

    #pragma unroll
    for (int ks = 0; ks < 8; ks++) {
        short8 af = *(const short8*)&xls[l15][ks * 32 + quad * 8];
        #pragma unroll
        for (int nt = 0; nt < 4; nt++) {
            short8 bf = *(const short8*)(wswz +
                ((long)((ks * 16 + wave * 4 + nt) * 64 + lane)) * 8);
            acc[nt] = __builtin_amdgcn_mfma_f32_16x16x32_bf16(af, bf, acc[nt], 0, 0, 0);
        }
    }

    // hswz store (B-frag order for k_attn)
    int q0 = (quad & 1) * 4;
    int qd = ((row0 & 31) + quad * 4) >> 3;
    long bj32 = row0 >> 5;
    #pragma unroll
    for (int nt = 0; nt < 4; nt++) {
        int dg = wave * 4 + nt;
        long idx8 = (bj32 * 16 + dg) * 64 + qd * 16 + l15;
        ushort4 o = {f2bf(acc[nt][0]), f2bf(acc[nt][1]),
                     f2bf(acc[nt][2]), f2bf(acc[nt][3])};
        *(ushort4*)&hswz[idx8 * 8 + q0] = o;
    }

    // fused scores, pre-scaled by log2(e)
    float as_[4], ad_[4];
    #pragma unroll
    for (int nt = 0; nt < 4; nt++) {
        int d = nt * 16 + l15;
        as_[nt] = a[d * NH_ + wave];
        ad_[nt] = a[(64 + d) * NH_ + wave];
    }
    #pragma unroll
    for (int r = 0; r < 4; r++) {
        float ps = acc[0][r] * as_[0] + acc[1][r] * as_[1]
                 + acc[2][r] * as_[2] + acc[3][r] * as_[3];
        float pd = acc[0][r] * ad_[0] + acc[1][r] * ad_[1]
                 + acc[2][r] * ad_[2] + acc[3][r] * ad_[3];
        #pragma unroll
        for (int m = 1; m < 16; m <<= 1) {
            ps += __shfl_xor(ps, m);
            pd += __shfl_xor(pd, m);
        }
        if (l15 == 0) {
            int row = n0 + quad * 4 + r;
            ssrc[((long)b * NH_ + wave) * N_ + row] = ps * L2E;
            sdst[((long)b * NH_ + wave) * N_ + row] = pd * L2E;
        }
    }
}

// ---------------------------------------------------------------------------
// Kernel C: masked softmax + MFMA aggregate.
// grid = 16 b * 32 rowgroups(32 rows) = 512 blocks x 512 thr = 8 waves
// (hh = wave&3, jh = wave>>2). Each wave: 2 i-strips (B-frags reused),
// denominator via all-ones-B MFMA (lands den(row) in the owning lane).
// ---------------------------------------------------------------------------
__global__ __launch_bounds__(512, 4) void k_attn(
    const unsigned int* __restrict__ pb, const unsigned short* __restrict__ hswz,
    const float* __restrict__ ssrc, const float* __restrict__ sdst,
    float* __restrict__ out)
{
    __shared__ float ss_s[4][32];
    __shared__ float accb[4][2][64][20];   // [hh][strip][lane][16 acc + 4 den]

    int t = threadIdx.x;
    int b  = blockIdx.x >> 5, ig = blockIdx.x & 31;
    int i0 = ig * 32;
    int wave = t >> 6, lane = t & 63, quad = lane >> 4, l15 = lane & 15;
    int hh = wave & 3, jh = wave >> 2;

    if (t < 128) {
        int h = t >> 5, i = t & 31;
        ss_s[h][i] = ssrc[((long)(b * NH_ + h)) * N_ + i0 + i];
    }
    __syncthreads();

    float ss0 = ss_s[hh][l15];
    float ss1 = ss_s[hh][16 + l15];
    const float* sdp = sdst + ((long)(b * NH_ + hh)) * N_ + jh * 512;
    long grow0 = ((long)b << 10) + i0 + l15;
    const unsigned int* pb0 = pb + (grow0 << 5) + jh * 16;
    const unsigned int* pb1 = pb0 + (16 << 5);

    f32x4 acc0[4], acc1[4], dn0, dn1;
    #pragma unroll
    for (int i = 0; i < 4; i++) {
        acc0[i] = (f32x4){0.f, 0.f, 0.f, 0.f};
        acc1[i] = (f32x4){0.f, 0.f, 0.f, 0.f};
    }
    dn0 = (f32x4){0.f, 0.f, 0.f, 0.f};
    dn1 = (f32x4){0.f, 0.f, 0.f, 0.f};
    short8 ones;
    #pragma unroll
    for (int i = 0; i < 8; i++) ones[i] = (short)0x3F80;   // bf16 1.0

    int shq = quad * 8;

    #pragma unroll 4
    for (int jc = 0; jc < 16; jc++) {
        unsigned int m0 = (pb0[jc] >> shq) & 0xffu;
        unsigned int m1 = (pb1[jc] >> shq) & 0xffu;
        const float* sj = sdp + jc * 32 + quad * 8;
        float4 sA = *(const float4*)sj;
        float4 sB = *(const float4*)(sj + 4);
        float sv[8] = {sA.x, sA.y, sA.z, sA.w, sB.x, sB.y, sB.z, sB.w};

        union { unsigned int u[4]; short8 s; } p0, p1;
        #pragma unroll
        for (int qp = 0; qp < 4; qp++) {
            unsigned int wb[2][2];
            #pragma unroll
            for (int hv = 0; hv < 2; hv++) {
                int q = 2 * qp + hv;
                float e0 = ss0 + sv[q];
                float w0 = __builtin_exp2f(fmaxf(e0, 0.2f * e0));
                w0 = ((m0 >> q) & 1u) ? w0 : 0.f;
                float e1 = ss1 + sv[q];
                float w1 = __builtin_exp2f(fmaxf(e1, 0.2f * e1));
                w1 = ((m1 >> q) & 1u) ? w1 : 0.f;
                wb[0][hv] = __float_as_uint(w0) + 0x8000u;   // round-half-up
                wb[1][hv] = __float_as_uint(w1) + 0x8000u;
            }
            p0.u[qp] = (wb[0][1] & 0xffff0000u) | (wb[0][0] >> 16);
            p1.u[qp] = (wb[1][1] & 0xffff0000u) | (wb[1][0] >> 16);
        }

        long s8 = ((long)(b * 32 + jh * 16 + jc)) * 1024;
        #pragma unroll
        for (int idt = 0; idt < 4; idt++) {
            short8 bf = *(const short8*)(hswz + (s8 + (hh * 4 + idt) * 64 + lane) * 8);
            acc0[idt] = __builtin_amdgcn_mfma_f32_16x16x32_bf16(p0.s, bf, acc0[idt], 0, 0, 0);
            acc1[idt] = __builtin_amdgcn_mfma_f32_16x16x32_bf16(p1.s, bf, acc1[idt], 0, 0, 0);
        }
        dn0 = __builtin_amdgcn_mfma_f32_16x16x32_bf16(p0.s, ones, dn0, 0, 0, 0);
        dn1 = __builtin_amdgcn_mfma_f32_16x16x32_bf16(p1.s, ones, dn1, 0, 0, 0);
    }

    if (jh == 1) {
        #pragma unroll
        for (int idt = 0; idt < 4; idt++) {
            *(f32x4*)&accb[hh][0][lane][idt * 4] = acc0[idt];
            *(f32x4*)&accb[hh][1][lane][idt * 4] = acc1[idt];
        }
        *(f32x4*)&accb[hh][0][lane][16] = dn0;
        *(f32x4*)&accb[hh][1][lane][16] = dn1;
    }
    __syncthreads();

    if (jh == 0) {
        f32x4 od0 = *(const f32x4*)&accb[hh][0][lane][16];
        f32x4 od1 = *(const f32x4*)&accb[hh][1][lane][16];
        float inv0[4], inv1[4];
        #pragma unroll
        for (int r = 0; r < 4; r++) {
            inv0[r] = 1.0f / (dn0[r] + od0[r]);
            inv1[r] = 1.0f / (dn1[r] + od1[r]);
        }
        #pragma unroll
        for (int idt = 0; idt < 4; idt++) {
            f32x4 o0 = *(const f32x4*)&accb[hh][0][lane][idt * 4];
            f32x4 o1 = *(const f32x4*)&accb[hh][1][lane][idt * 4];
            int col = hh * 64 + idt * 16 + l15;
            #pragma unroll
            for (int r = 0; r < 4; r++) {
                long row_g = (long)b * N_ + i0 + quad * 4 + r;
                out[row_g * HD_ + col] = (acc0[idt][r] + o0[r]) * inv0[r];
                out[(row_g + 16) * HD_ + col] = (acc1[idt][r] + o1[r]) * inv1[r];
            }
        }
    }
}

extern "C" void kernel_launch(void* const* d_in, const int* in_sizes, int n_in,
                              void* d_out, int out_size, void* d_ws, size_t ws_size,
                              hipStream_t stream) {
    const float* x   = (const float*)d_in[0];
    const int*   adj = (const int*)d_in[1];
    const float* W   = (const float*)d_in[2];
    const float* a   = (const float*)d_in[3];
    float* out = (float*)d_out;

    unsigned int* pb      = (unsigned int*)d_ws;                       // 2 MB
    unsigned short* hswz  = (unsigned short*)(pb + 524288);            // 8 MB
    unsigned short* wswz  = hswz + (long)B_ * N_ * HD_;                // 128 KB
    float* ssrc = (float*)(wswz + INF_ * HD_);
    float* sdst = ssrc + (long)B_ * NH_ * N_;

    k_prep<<<2080, 256, 0, stream>>>(adj, W, pb, wswz);
    k_gemm_h<<<1024, 256, 0, stream>>>(x, a, wswz, hswz, ssrc, sdst);
    k_attn<<<512, 512, 0, stream>>>(pb, hswz, ssrc, sdst, out);
}